// Round 8
// baseline (510.805 us; speedup 1.0000x reference)
//
#include <hip/hip_runtime.h>

#define CH    256
#define NTOK  2304
#define MATSZ (CH * NTOK)   // 589824 elements per (b, matrix)

typedef __bf16 bf16x8 __attribute__((ext_vector_type(8)));
typedef float  f4v    __attribute__((ext_vector_type(4)));
typedef unsigned int u32x4 __attribute__((ext_vector_type(4)));

__device__ __forceinline__ unsigned short f2bf(float f) {
    union { float f; unsigned int i; } c;
    c.f = f;
    unsigned int x = c.i;
    x += 0x7fffu + ((x >> 16) & 1u);   // round-to-nearest-even
    return (unsigned short)(x >> 16);
}

__device__ __forceinline__ bf16x8 cvt8(const float* p) {
    union { bf16x8 v; unsigned short s[8]; } u;
#pragma unroll
    for (int i = 0; i < 8; ++i) u.s[i] = f2bf(p[i]);
    return u.v;
}

// ---------------------------------------------------------------------------
// 64x64-tiled transpose + fp32->bf16 (unchanged, HW-verified).
// ---------------------------------------------------------------------------
__global__ __launch_bounds__(256) void tpose_k(
    const float* __restrict__ inL,
    const float* __restrict__ inR,
    unsigned short* __restrict__ out, int R, int Ccols)
{
    __shared__ unsigned short tile[64][72];
    int mat = blockIdx.y;
    const float* in = (mat >= 8 ? inR : inL) + (size_t)(mat & 7) * MATSZ;
    unsigned short* o = out + (size_t)mat * MATSZ;
    int tC = Ccols >> 6;
    int r0 = (blockIdx.x / tC) << 6;
    int c0 = (blockIdx.x % tC) << 6;
    int t = threadIdx.x;
    int col = t & 63, rs = t >> 6;
#pragma unroll
    for (int i = 0; i < 16; ++i) {
        int row = rs + i * 4;
        tile[row][col] = f2bf(in[(size_t)(r0 + row) * Ccols + c0 + col]);
    }
    __syncthreads();
#pragma unroll
    for (int i = 0; i < 16; ++i) {
        int crow = rs + i * 4;
        o[(size_t)(c0 + crow) * R + r0 + col] = tile[col][crow];
    }
}

// ---------------------------------------------------------------------------
// Projection (unchanged, HW-verified).
// ---------------------------------------------------------------------------
__global__ __launch_bounds__(256, 2) void proj_k(
    const unsigned short* __restrict__ XT,   // [2][8][2304][256] bf16
    const float* __restrict__ Wq_, const float* __restrict__ Wk_,
    const float* __restrict__ bq_, const float* __restrict__ bk_,
    const float* __restrict__ gq_, const float* __restrict__ gk_,
    const float* __restrict__ beq_, const float* __restrict__ bek_,
    const float* __restrict__ mq_, const float* __restrict__ mk_,
    const float* __restrict__ vq_, const float* __restrict__ vk_,
    unsigned short* __restrict__ Yout)       // [4][8][MATSZ] bf16
{
    __shared__ __align__(16) unsigned short Xs[64][264];
    int pb = blockIdx.y;
    int p = pb >> 3, b = pb & 7;
    int s = p & 1, br = p >> 1;
    const unsigned short* X = XT + (size_t)(s * 8 + b) * MATSZ;
    const float* W  = br ? Wk_ : Wq_;
    const float* bb = br ? bk_ : bq_;
    const float* gg = br ? gk_ : gq_;
    const float* be = br ? bek_ : beq_;
    const float* mm = br ? mk_ : mq_;
    const float* vv = br ? vk_ : vq_;
    unsigned short* Yo = Yout + (size_t)pb * MATSZ;

    int ot = blockIdx.x & 3, pt = blockIdx.x >> 2;
    int o0 = ot * 64, pos0 = pt * 64;
    int t = threadIdx.x;
    int w = t >> 6, lane = t & 63;
    int l15 = lane & 15, quad = lane >> 4;

    {   // stage XT tile: 64 pos-rows x 256 c
        int r = t >> 2, cq = (t & 3) << 6;
        const unsigned short* src = X + (size_t)(pos0 + r) * CH + cq;
        unsigned short* dst = &Xs[r][cq];
#pragma unroll
        for (int k = 0; k < 8; ++k)
            *(u32x4*)(dst + k * 8) = *(const u32x4*)(src + k * 8);
    }
    bf16x8 wf[8];
    {
        const float* wp = W + (size_t)(o0 + w * 16 + l15) * CH + quad * 8;
#pragma unroll
        for (int kc = 0; kc < 8; ++kc)
            wf[kc] = cvt8(wp + kc * 32);
    }
    __syncthreads();

    f4v zero4 = {0.f, 0.f, 0.f, 0.f};
    f4v acc[4] = {zero4, zero4, zero4, zero4};
#pragma unroll
    for (int kc = 0; kc < 8; ++kc) {
#pragma unroll
        for (int ct = 0; ct < 4; ++ct) {
            bf16x8 xb = *(const bf16x8*)(&Xs[ct * 16 + l15][kc * 32 + quad * 8]);
            acc[ct] = __builtin_amdgcn_mfma_f32_16x16x32_bf16(wf[kc], xb, acc[ct], 0, 0, 0);
        }
    }
#pragma unroll
    for (int r = 0; r < 4; ++r) {
        int o = o0 + w * 16 + quad * 4 + r;
        float scale = gg[o] * rsqrtf(vv[o] + 1e-5f);
        float shift = (bb[o] - mm[o]) * scale + be[o];
#pragma unroll
        for (int ct = 0; ct < 4; ++ct) {
            float val = acc[ct][r] * scale + shift;
            Yo[(size_t)o * NTOK + pos0 + ct * 16 + l15] = f2bf(val);
        }
    }
}

// ---------------------------------------------------------------------------
// Fused attention, 2x2 wave decomposition to halve LDS read traffic.
// Block = 64 q-rows, K-loop over 36 x 64-key tiles.
// wave(i,j), i=w>>1, j=w&1:
//   QK^T: q-rows 32i..+32 (Q in regs, 2 m-tiles) x keys 32j..+32 -> each wave
//         reads only half the K tile.
//   PV:   q-rows 32i..+32 x channels 128j..+128 -> half of V, half of P.
// l row-sums: per-wave partials over the wave's 32 keys, combined in epilogue.
// P bridge is cross-wave -> __syncthreads before PV. FP32 output.
// ---------------------------------------------------------------------------
__global__ __launch_bounds__(256, 2) void attn_k(
    const unsigned short* __restrict__ Y,    // [4][8][MATSZ] projections bf16
    const unsigned short* __restrict__ VT,   // [2][8][256][2304] bf16
    float* __restrict__ out)                 // [2][8][MATSZ] fp32
{
    // Ks 64x264 (33792B) | Vs 256x72 (36864B) | Ps 64x72 (9216B) = 79872B
    __shared__ __align__(16) unsigned short lds[64 * 264 + 256 * 72 + 64 * 72];
    unsigned short* Ks = lds;
    unsigned short* Vs = lds + 64 * 264;
    unsigned short* Ps = lds + 64 * 264 + 256 * 72;

    int ab = blockIdx.y;
    int a = ab >> 3, b = ab & 7;
    int qt = blockIdx.x;
    const unsigned short* Qp = Y + (size_t)(a * 8 + b) * MATSZ;        // q(l)/q(r)
    const unsigned short* Kp = Y + (size_t)((3 - a) * 8 + b) * MATSZ;  // k(r)/k(l)
    const unsigned short* Vp = VT + (size_t)((1 - a) * 8 + b) * MATSZ;
    float* Op = out + (size_t)ab * MATSZ;

    int t = threadIdx.x;
    int w = t >> 6, lane = t & 63;
    int l15 = lane & 15, quad = lane >> 4;
    int wi = w >> 1, wj = w & 1;

    // staging coordinates (HW-verified in R6/R7)
    int kr = t >> 2, kc0 = (t & 3) << 6;               // K: row, col-quarter
    int vc = ((t & 3) << 6) + (t >> 2);                // V: channel row
    const unsigned short* ksrc0 = Kp + (size_t)kr * CH + kc0;
    const unsigned short* vsrc0 = Vp + (size_t)vc * NTOK;
    unsigned short* kdst = Ks + kr * 264 + kc0;
    unsigned short* vdst = Vs + vc * 72;

    // Q fragments: 32 q-rows = 2 m-tiles, cached in registers
    bf16x8 qf[2][8];
#pragma unroll
    for (int mi = 0; mi < 2; ++mi) {
        const unsigned short* qp =
            Qp + (size_t)(qt * 64 + wi * 32 + mi * 16 + l15) * CH + quad * 8;
#pragma unroll
        for (int kc = 0; kc < 8; ++kc) qf[mi][kc] = *(const bf16x8*)(qp + kc * 32);
    }
    f4v zero4 = {0.f, 0.f, 0.f, 0.f};
    f4v acc_o[2][8];
#pragma unroll
    for (int mi = 0; mi < 2; ++mi)
#pragma unroll
        for (int ni = 0; ni < 8; ++ni) acc_o[mi][ni] = zero4;
    float l_acc[2][4] = {{0.f, 0.f, 0.f, 0.f}, {0.f, 0.f, 0.f, 0.f}};
    __bf16* Psb = (__bf16*)Ps;

    // preload tile kt=0 into registers
    u32x4 kreg[8], vreg[8];
#pragma unroll
    for (int k = 0; k < 8; ++k) kreg[k] = *(const u32x4*)(ksrc0 + k * 8);
#pragma unroll
    for (int k = 0; k < 8; ++k) vreg[k] = *(const u32x4*)(vsrc0 + k * 8);

    for (int kt = 0; kt < 36; ++kt) {
        __syncthreads();     // B1: previous iteration's LDS readers done
#pragma unroll
        for (int k = 0; k < 8; ++k) *(u32x4*)(kdst + k * 8) = kreg[k];
#pragma unroll
        for (int k = 0; k < 8; ++k) *(u32x4*)(vdst + k * 8) = vreg[k];
        __syncthreads();     // B2: staged tile visible

        if (kt < 35) {       // prefetch kt+1; compute hides the latency
            const unsigned short* kn = ksrc0 + (size_t)(kt + 1) * 64 * CH;
            const unsigned short* vn = vsrc0 + (size_t)(kt + 1) * 64;
#pragma unroll
            for (int k = 0; k < 8; ++k) kreg[k] = *(const u32x4*)(kn + k * 8);
#pragma unroll
            for (int k = 0; k < 8; ++k) vreg[k] = *(const u32x4*)(vn + k * 8);
        }

        // S = Q K^T : 32 q-rows x 32 keys (keys 32*wj ..)
        f4v accs[2][2] = {{zero4, zero4}, {zero4, zero4}};
#pragma unroll
        for (int kc = 0; kc < 8; ++kc) {
#pragma unroll
            for (int nt = 0; nt < 2; ++nt) {
                bf16x8 kf = *(const bf16x8*)(
                    Ks + (wj * 32 + nt * 16 + l15) * 264 + kc * 32 + quad * 8);
#pragma unroll
                for (int mi = 0; mi < 2; ++mi)
                    accs[mi][nt] = __builtin_amdgcn_mfma_f32_16x16x32_bf16(
                        qf[mi][kc], kf, accs[mi][nt], 0, 0, 0);
            }
        }
        // P = exp(S/256); partial row-sums over this wave's 32 keys; P -> LDS
#pragma unroll
        for (int mi = 0; mi < 2; ++mi)
#pragma unroll
            for (int r = 0; r < 4; ++r) {
                int q = wi * 32 + mi * 16 + quad * 4 + r;
                float rs = 0.f;
#pragma unroll
                for (int nt = 0; nt < 2; ++nt) {
                    float pe = __expf(accs[mi][nt][r] * (1.0f / 256.0f));
                    rs += pe;
                    Psb[q * 72 + wj * 32 + nt * 16 + l15] = (__bf16)pe;
                }
                rs += __shfl_xor(rs, 1, 64);
                rs += __shfl_xor(rs, 2, 64);
                rs += __shfl_xor(rs, 4, 64);
                rs += __shfl_xor(rs, 8, 64);
                l_acc[mi][r] += rs;
            }
        __syncthreads();     // B3: P complete (cross-wave A-frags)

        // O += P @ V : q-rows 32*wi.. x channels 128*wj..
#pragma unroll
        for (int kk = 0; kk < 2; ++kk) {
            bf16x8 pf[2];
#pragma unroll
            for (int mi = 0; mi < 2; ++mi)
                pf[mi] = *(const bf16x8*)(
                    Ps + (wi * 32 + mi * 16 + l15) * 72 + kk * 32 + quad * 8);
#pragma unroll
            for (int ni = 0; ni < 8; ++ni) {
                bf16x8 vf = *(const bf16x8*)(
                    Vs + (wj * 128 + ni * 16 + l15) * 72 + kk * 32 + quad * 8);
#pragma unroll
                for (int mi = 0; mi < 2; ++mi)
                    acc_o[mi][ni] = __builtin_amdgcn_mfma_f32_16x16x32_bf16(
                        pf[mi], vf, acc_o[mi][ni], 0, 0, 0);
            }
        }
    }

    // epilogue: combine l partials across wj, normalize, transpose, store
    __syncthreads();
    float* Ot = (float*)lds;                  // [256][73] fp32 = 74752B
    float* Lp = (float*)lds + 256 * 73;       // [64][2] partial sums (512B)
    if (l15 == 0) {
#pragma unroll
        for (int mi = 0; mi < 2; ++mi)
#pragma unroll
            for (int r = 0; r < 4; ++r)
                Lp[(wi * 32 + mi * 16 + quad * 4 + r) * 2 + wj] = l_acc[mi][r];
    }
    __syncthreads();
#pragma unroll
    for (int mi = 0; mi < 2; ++mi)
#pragma unroll
        for (int r = 0; r < 4; ++r) {
            int q = wi * 32 + mi * 16 + quad * 4 + r;
            float linv = 1.0f / (Lp[q * 2] + Lp[q * 2 + 1]);
#pragma unroll
            for (int ni = 0; ni < 8; ++ni) {
                int c = wj * 128 + ni * 16 + l15;
                Ot[c * 73 + q] = acc_o[mi][ni][r] * linv;
            }
        }
    __syncthreads();
    for (int cg = 0; cg < 64; ++cg) {
        int c = cg * 4 + w;
        Op[(size_t)c * NTOK + qt * 64 + lane] = Ot[c * 73 + lane];
    }
}

// ---------------------------------------------------------------------------
extern "C" void kernel_launch(void* const* d_in, const int* in_sizes, int n_in,
                              void* d_out, int out_size, void* d_ws, size_t ws_size,
                              hipStream_t stream) {
    (void)in_sizes; (void)n_in; (void)out_size; (void)ws_size;
    const float* feaL  = (const float*)d_in[0];
    const float* feaR  = (const float*)d_in[1];
    const float* Wq    = (const float*)d_in[2];
    const float* bq    = (const float*)d_in[3];
    const float* gq    = (const float*)d_in[4];
    const float* betaq = (const float*)d_in[5];
    const float* mq    = (const float*)d_in[6];
    const float* vq    = (const float*)d_in[7];
    const float* Wk    = (const float*)d_in[8];
    const float* bk    = (const float*)d_in[9];
    const float* gk    = (const float*)d_in[10];
    const float* betak = (const float*)d_in[11];
    const float* mk    = (const float*)d_in[12];
    const float* vk    = (const float*)d_in[13];

    // workspace (bf16): XT/VT alias 16*MATSZ (18.9MB) | Y 32*MATSZ (37.7MB)
    unsigned short* XT = (unsigned short*)d_ws;   // reused as VT after proj
    unsigned short* VT = XT;
    unsigned short* Yb = XT + (size_t)16 * MATSZ;
    float* out = (float*)d_out;   // fp32: reference output dtype

    dim3 blk(256);
    // XT[s][b][pos][c] = fea[b][c][pos]
    tpose_k<<<dim3(144, 16), blk, 0, stream>>>(feaL, feaR, XT, 256, 2304);
    proj_k<<<dim3(144, 32), blk, 0, stream>>>(XT, Wq, Wk, bq, bk, gq, gk,
                                              betaq, betak, mq, mk, vq, vk, Yb);
    // VT[s][b][c][n] = fea_flat[n*256+c]
    tpose_k<<<dim3(144, 16), blk, 0, stream>>>(feaL, feaR, VT, 2304, 256);
    attn_k<<<dim3(36, 16), blk, 0, stream>>>(Yb, VT, out);
}